// Round 5
// baseline (429.830 us; speedup 1.0000x reference)
//
#include <hip/hip_runtime.h>
#include <hip/hip_bf16.h>

typedef __hip_bfloat16 bf16;
typedef unsigned short ushort_t;
typedef __attribute__((ext_vector_type(8))) short short8;
typedef __attribute__((ext_vector_type(4))) float float4v;

#define BATCH 4
#define HH 512
#define WW 512

__device__ __forceinline__ ushort_t f2bfu(float f) {
  __hip_bfloat16 h = __float2bfloat16(f);
  union { __hip_bfloat16 h; ushort_t u; } c;
  c.h = h;
  return c.u;
}
__device__ __forceinline__ float bfu2f(ushort_t u) {
  return __uint_as_float(((unsigned)u) << 16);
}

// async global->LDS DMA, 16 B per lane; LDS dest = wave-uniform base + lane*16
__device__ __forceinline__ void dma16(void* lds, const void* g) {
  __builtin_amdgcn_global_load_lds(
      (const __attribute__((address_space(1))) unsigned int*)g,
      (__attribute__((address_space(3))) unsigned int*)lds, 16, 0, 0);
}

// ---------------------------------------------------------------------------
// Weight prep: w[l] OIHW f32  ->  wT[l] = [tap(9)][COUT_PAD][CIN_PAD] bf16
// ---------------------------------------------------------------------------
struct WP { const float* w[8]; };

__global__ __launch_bounds__(256) void prep_w(WP wp, bf16* __restrict__ dst) {
  const int O[8]   = {32, 32, 64, 64, 64, 32, 32, 2};
  const int I[8]   = {3, 32, 32, 64, 64, 64, 32, 32};
  const int OP[8]  = {32, 32, 64, 64, 64, 32, 32, 16};
  const int IP[8]  = {32, 32, 32, 64, 64, 64, 32, 32};
  const int OFF[8] = {0, 9216, 18432, 36864, 73728, 110592, 129024, 138240};
  int l = blockIdx.y;
  int e = blockIdx.x * 256 + threadIdx.x;
  int n = 9 * OP[l] * IP[l];
  if (e >= n) return;
  int tap = e / (OP[l] * IP[l]);
  int rem = e - tap * OP[l] * IP[l];
  int o = rem / IP[l];
  int i = rem - o * IP[l];
  float v = 0.0f;
  if (o < O[l] && i < I[l]) v = wp.w[l][((o * I[l]) + i) * 9 + tap];
  dst[OFF[l] + e] = __float2bfloat16(v);
}

// ---------------------------------------------------------------------------
// pack_x: NCHW f32 (3ch) -> NHWC-8 bf16 (ch 3..7 zero)
// ---------------------------------------------------------------------------
__global__ __launch_bounds__(256) void pack_x(const float* __restrict__ x,
                                              bf16* __restrict__ xp) {
  int i = blockIdx.x * 256 + threadIdx.x;  // over B*H*W
  if (i >= BATCH * HH * WW) return;
  int b = i / (HH * WW);
  int px = i - b * (HH * WW);
  union { uint4 v; ushort_t s[8]; } o;
  o.v = make_uint4(0, 0, 0, 0);
  const float* p = x + (long)b * 3 * HH * WW + px;
  o.s[0] = f2bfu(p[0]);
  o.s[1] = f2bfu(p[HH * WW]);
  o.s[2] = f2bfu(p[2 * HH * WW]);
  *(uint4*)&xp[(long)i * 8] = o.v;
}

// ---------------------------------------------------------------------------
// Implicit-GEMM 3x3 conv (pad 1) via mfma_f32_16x16x32_bf16, NHWC bf16 acts.
// Block: 256 thr (4 waves), 16 x (4*NT) OUTPUT tile; wave w rows NT*w..NT*w+NT-1.
// Weights are NOT staged in LDS: A-fragments load per-tap from global
// (L1/L2-resident, all waves hit the same lines). LDS = input halo only.
// IN_MODE:  0 = NHWC bf16 same-res (DMA fast path for interior blocks)
//           2 = NHWC bf16 HALF-res source, fused x2 bilinear upsample staging
//           3 = NHWC-8 packed bf16 (conv0; ch 8..31 zero)
// OUT_MODE: 0 = NHWC bf16 (+relu)
//           2 = flow NCHW f32 (tanh) + fused deformed [B,H,W,2]
//           3 = NHWC bf16, fused relu + 2x2 maxpool (writes H/2 x W/2)
// ---------------------------------------------------------------------------
template <int CIN, int COUT, int COUTR, int NT, int ACT, int IN_MODE,
          int OUT_MODE>
__global__ __launch_bounds__(256) void conv_mfma(
    const void* __restrict__ in_, const bf16* __restrict__ wt,
    const float* __restrict__ bias, void* __restrict__ out_, int H, int W,
    const float* __restrict__ temp, float* __restrict__ def) {
  constexpr int MT = COUT / 16;
  constexpr int CK = 32;
  constexpr int TH = 4 * NT;   // tile height
  constexpr int HR = TH + 2;   // halo rows
  __shared__ alignas(16) bf16 in_lds[HR * 18 * CK];

  const int tid = threadIdx.x;
  const int lane = tid & 63;
  const int wid = tid >> 6;
  const int lm = lane & 15;
  const int quad = lane >> 4;
  const int x0 = blockIdx.x * 16;
  const int y0 = blockIdx.y * TH;
  const int b = blockIdx.z;

  float4v acc[MT][NT];
#pragma unroll
  for (int mt = 0; mt < MT; ++mt) {
    float4v bv;
    if constexpr (COUTR == COUT) {
      bv = *(const float4v*)(bias + mt * 16 + quad * 4);
    } else {
#pragma unroll
      for (int r = 0; r < 4; ++r) {
        int co = mt * 16 + quad * 4 + r;
        bv[r] = (co < COUTR) ? bias[co] : 0.0f;
      }
    }
#pragma unroll
    for (int nt = 0; nt < NT; ++nt) acc[mt][nt] = bv;
  }

  for (int c0 = 0; c0 < CIN; c0 += CK) {
    // ---- stage input halo tile into LDS ----
    if constexpr (IN_MODE == 3) {
      // packed NHWC-8 source; segs 1..3 zero
      const bf16* in = (const bf16*)in_;
      for (int u = tid; u < HR * 18 * 4; u += 256) {
        int px = u >> 2;
        int seg = u & 3;
        int hy = px / 18, hx = px - hy * 18;
        int gy = y0 - 1 + hy, gx = x0 - 1 + hx;
        uint4 v = make_uint4(0, 0, 0, 0);
        if (seg == 0 && gy >= 0 && gy < H && gx >= 0 && gx < W)
          v = *(const uint4*)(in + (((long)b * H + gy) * W + gx) * 8);
        *(uint4*)&in_lds[px * CK + seg * 8] = v;
      }
    } else if constexpr (IN_MODE == 2) {
      // fused x2 bilinear upsample from half-res NHWC source (edge clamp),
      // zero outside full-res image (conv pad)
      const bf16* in = (const bf16*)in_;
      const int Hs = H >> 1, Ws = W >> 1;
      for (int u = tid; u < HR * 18 * 4; u += 256) {
        int px = u >> 2;
        int seg = u & 3;
        int hy = px / 18, hx = px - hy * 18;
        int gy = y0 - 1 + hy, gx = x0 - 1 + hx;
        uint4 o = make_uint4(0, 0, 0, 0);
        if (gy >= 0 && gy < H && gx >= 0 && gx < W) {
          int ys = (gy >> 1) - ((gy & 1) ? 0 : 1);
          int xs = (gx >> 1) - ((gx & 1) ? 0 : 1);
          float wy = (gy & 1) ? 0.25f : 0.75f;
          float wx = (gx & 1) ? 0.25f : 0.75f;
          int y0c = max(ys, 0), y1c = min(ys + 1, Hs - 1);
          int x0c = max(xs, 0), x1c = min(xs + 1, Ws - 1);
          const bf16* p = in + ((long)b * Hs * Ws) * CIN + c0 + seg * 8;
          union { uint4 v; ushort_t s[8]; } a00, a01, a10, a11, r;
          a00.v = *(const uint4*)(p + ((long)y0c * Ws + x0c) * CIN);
          a01.v = *(const uint4*)(p + ((long)y0c * Ws + x1c) * CIN);
          a10.v = *(const uint4*)(p + ((long)y1c * Ws + x0c) * CIN);
          a11.v = *(const uint4*)(p + ((long)y1c * Ws + x1c) * CIN);
#pragma unroll
          for (int j = 0; j < 8; ++j) {
            float f = (1.0f - wy) * ((1.0f - wx) * bfu2f(a00.s[j]) +
                                     wx * bfu2f(a01.s[j])) +
                      wy * ((1.0f - wx) * bfu2f(a10.s[j]) +
                            wx * bfu2f(a11.s[j]));
            r.s[j] = f2bfu(f);
          }
          o = r.v;
        }
        *(uint4*)&in_lds[px * CK + seg * 8] = o;
      }
    } else {
      const bool interior =
          (x0 >= 1) && (x0 + 16 <= W - 1) && (y0 >= 1) && (y0 + TH <= H - 1);
      const bf16* in = (const bf16*)in_;
      if (interior) {
        // core: one DMA per halo row (16 px x 64 B = 1 KiB = 64 lanes x 16 B)
        for (int r = wid; r < HR; r += 4) {
          int gy = y0 - 1 + r;
          const bf16* gsrc = in + (((long)b * H + gy) * W + x0) * CIN + c0 +
                             (lane >> 2) * CIN + (lane & 3) * 8;
          dma16(&in_lds[(r * 18 + 1) * CK], gsrc);
        }
        // x-halo: 2 columns x HR rows x 4 segs
        for (int u = tid; u < 8 * HR; u += 256) {
          int r = u >> 3;
          int side = (u >> 2) & 1;
          int seg = u & 3;
          int gx = side ? (x0 + 16) : (x0 - 1);
          int gy = y0 - 1 + r;
          uint4 v = *(const uint4*)(in + (((long)b * H + gy) * W + gx) * CIN +
                                    c0 + seg * 8);
          *(uint4*)&in_lds[(r * 18 + (side ? 17 : 0)) * CK + seg * 8] = v;
        }
      } else {
        for (int u = tid; u < HR * 18 * 4; u += 256) {
          int px = u >> 2;
          int seg = u & 3;
          int hy = px / 18, hx = px - hy * 18;
          int gy = y0 - 1 + hy, gx = x0 - 1 + hx;
          uint4 v = make_uint4(0, 0, 0, 0);
          if (gy >= 0 && gy < H && gx >= 0 && gx < W)
            v = *(const uint4*)(in + (((long)b * H + gy) * W + gx) * CIN + c0 +
                                seg * 8);
          *(uint4*)&in_lds[px * CK + seg * 8] = v;
        }
      }
    }
    __syncthreads();

    // ---- 9 taps x K=32 MFMA; A-fragments straight from global (L1/L2) ----
#pragma unroll
    for (int tap = 0; tap < 9; ++tap) {
      const int r = tap / 3, s = tap - r * 3;
      short8 afrag[MT], bfrag[NT];
#pragma unroll
      for (int mt = 0; mt < MT; ++mt)
        afrag[mt] = *(const short8*)&wt[((long)tap * COUT + mt * 16 + lm) * CIN +
                                        c0 + quad * 8];
#pragma unroll
      for (int nt = 0; nt < NT; ++nt) {
        int py = NT * wid + nt;
        bfrag[nt] =
            *(const short8*)&in_lds[((py + r) * 18 + lm + s) * CK + quad * 8];
      }
#pragma unroll
      for (int mt = 0; mt < MT; ++mt)
#pragma unroll
        for (int nt = 0; nt < NT; ++nt)
          acc[mt][nt] = __builtin_amdgcn_mfma_f32_16x16x32_bf16(
              afrag[mt], bfrag[nt], acc[mt][nt], 0, 0, 0);
    }
    __syncthreads();
  }

  // ---- epilogue ----
  if constexpr (OUT_MODE == 3) {
    // fused relu + 2x2 maxpool -> NHWC bf16 at H/2 x W/2
    bf16* out = (bf16*)out_;
    const int Ho = H >> 1, Wo = W >> 1;
#pragma unroll
    for (int mt = 0; mt < MT; ++mt) {
#pragma unroll
      for (int g = 0; g < NT / 2; ++g) {
        float4v m;
#pragma unroll
        for (int r = 0; r < 4; ++r)
          m[r] = fmaxf(fmaxf(acc[mt][2 * g][r], acc[mt][2 * g + 1][r]), 0.0f);
#pragma unroll
        for (int r = 0; r < 4; ++r) m[r] = fmaxf(m[r], __shfl_xor(m[r], 1, 64));
        if ((lm & 1) == 0) {
          int pyo = (y0 >> 1) + (NT / 2) * wid + g;
          int pxo = (x0 >> 1) + (lm >> 1);
          union { uint2 v; ushort_t s[4]; } pk;
#pragma unroll
          for (int r = 0; r < 4; ++r) pk.s[r] = f2bfu(m[r]);
          *(uint2*)&out[(((long)b * Ho + pyo) * Wo + pxo) * COUT + mt * 16 +
                        quad * 4] = pk.v;
        }
      }
    }
  } else {
#pragma unroll
    for (int mt = 0; mt < MT; ++mt) {
#pragma unroll
      for (int nt = 0; nt < NT; ++nt) {
        int gy = y0 + NT * wid + nt;
        int gx = x0 + lm;
        float4v v = acc[mt][nt];
        if constexpr (OUT_MODE == 0) {
          bf16* out = (bf16*)out_;
          union { uint2 v; ushort_t s[4]; } pk;
#pragma unroll
          for (int r = 0; r < 4; ++r) pk.s[r] = f2bfu(fmaxf(v[r], 0.0f));
          *(uint2*)&out[(((long)b * H + gy) * W + gx) * COUT + mt * 16 +
                        quad * 4] = pk.v;
        } else {
          // OUT_MODE 2: flow (NCHW f32, 2ch, tanh) + fused deformed [B,H,W,2]
          float* out = (float*)out_;
          if (quad == 0) {
            float fx = tanhf(v[0]);
            float fy = tanhf(v[1]);
            out[(((long)b * 2 + 0) * H + gy) * (long)W + gx] = fx;
            out[(((long)b * 2 + 1) * H + gy) * (long)W + gx] = fy;
            float T = temp[0];
            float2 d;
            d.x = -1.0f + gx * (2.0f / 511.0f) + fx * T;
            d.y = -1.0f + gy * (2.0f / 511.0f) + fy * T;
            *(float2*)&def[(((long)b * H + gy) * W + gx) * 2] = d;
          }
        }
      }
    }
  }
}

// ---------------------------------------------------------------------------
// patches: grid_sample bilinear, zeros padding -> out [B,256,3,64,64]
// ---------------------------------------------------------------------------
__global__ __launch_bounds__(256) void patches_k(const float* __restrict__ x,
                                                 const float* __restrict__ def,
                                                 float* __restrict__ out) {
  int i = blockIdx.x * 256 + threadIdx.x;
  int pj = i & 63;
  int t = i >> 6;
  int pi = t & 63;
  t >>= 6;
  int n = t & 255;
  int b = t >> 8;
  if (b >= BATCH) return;
  int hi = n >> 4, wi = n & 15;
  const float* dptr = def + (((long)b * HH + hi * 32) * WW + wi * 32) * 2;
  float cx = dptr[0], cy = dptr[1];
  float pgx = cx + (-1.0f + pj * (2.0f / 63.0f)) * 0.125f;
  float pgy = cy + (-1.0f + pi * (2.0f / 63.0f)) * 0.125f;
  float ix = ((pgx + 1.0f) * 512.0f - 1.0f) * 0.5f;
  float iy = ((pgy + 1.0f) * 512.0f - 1.0f) * 0.5f;
  float fx0 = floorf(ix), fy0 = floorf(iy);
  float wx1 = ix - fx0, wy1 = iy - fy0;
  int x0 = (int)fx0, y0 = (int)fy0;
  int x1 = x0 + 1, y1 = y0 + 1;
  bool vx0 = (x0 >= 0) && (x0 <= 511), vx1 = (x1 >= 0) && (x1 <= 511);
  bool vy0 = (y0 >= 0) && (y0 <= 511), vy1 = (y1 >= 0) && (y1 <= 511);
  int cx0 = min(max(x0, 0), 511), cx1 = min(max(x1, 0), 511);
  int cy0 = min(max(y0, 0), 511), cy1 = min(max(y1, 0), 511);
  float w00 = (1.0f - wx1) * (1.0f - wy1) * ((vx0 && vy0) ? 1.0f : 0.0f);
  float w01 = wx1 * (1.0f - wy1) * ((vx1 && vy0) ? 1.0f : 0.0f);
  float w10 = (1.0f - wx1) * wy1 * ((vx0 && vy1) ? 1.0f : 0.0f);
  float w11 = wx1 * wy1 * ((vx1 && vy1) ? 1.0f : 0.0f);
#pragma unroll
  for (int c = 0; c < 3; ++c) {
    const float* img = x + ((long)b * 3 + c) * (HH * WW);
    float v = img[cy0 * WW + cx0] * w00 + img[cy0 * WW + cx1] * w01 +
              img[cy1 * WW + cx0] * w10 + img[cy1 * WW + cx1] * w11;
    out[(((long)b * 256 + n) * 3 + c) * 4096 + pi * 64 + pj] = v;
  }
}

// ---------------------------------------------------------------------------

extern "C" void kernel_launch(void* const* d_in, const int* in_sizes, int n_in,
                              void* d_out, int out_size, void* d_ws,
                              size_t ws_size, hipStream_t stream) {
  const float* x = (const float*)d_in[0];
  WP wp;
  const float* bs[8];
  for (int i = 0; i < 8; ++i) {
    wp.w[i] = (const float*)d_in[1 + 2 * i];
    bs[i] = (const float*)d_in[2 + 2 * i];
  }
  const float* temp = (const float*)d_in[17];

  float* out = (float*)d_out;
  float* flow = out + 12582912;  // [B,2,512,512] f32
  float* def = out + 14680064;   // [B,512,512,2] f32

  // Transposed bf16 weights at the head of the patches region of d_out;
  // patches_k overwrites it LAST.
  bf16* wT = (bf16*)d_out;
  const int WOFF[8] = {0, 9216, 18432, 36864, 73728, 110592, 129024, 138240};

  const size_t bufElems = (size_t)BATCH * 512 * 512 * 32;
  bf16* A = (bf16*)d_ws;
  bf16* Bf = A + bufElems;
  bf16* xp = Bf + bufElems;  // packed NHWC-8 input, 16.8 MB

  prep_w<<<dim3(144, 8), 256, 0, stream>>>(wp, wT);
  {
    int total = BATCH * HH * WW;
    pack_x<<<(total + 255) / 256, 256, 0, stream>>>(x, xp);
  }

  // COUT=32 kernels: NT=8 (16x32 tile); COUT=64: NT=4 (16x16 tile)
  dim3 g512t(32, 16, BATCH);   // 512x512, tile 16x32
  dim3 g256t(16, 8, BATCH);    // 256x256, tile 16x32
  dim3 g256(16, 16, BATCH);    // 256x256, tile 16x16

  // conv0: xp (NHWC-8) -> A [512,512,32]
  conv_mfma<32, 32, 32, 8, 0, 3, 0>
      <<<g512t, 256, 0, stream>>>(xp, wT + WOFF[0], bs[0], A, 512, 512, nullptr, nullptr);
  // conv1 + relu + pool: A -> Bf [256,256,32]
  conv_mfma<32, 32, 32, 8, 0, 0, 3>
      <<<g512t, 256, 0, stream>>>(A, wT + WOFF[1], bs[1], Bf, 512, 512, nullptr, nullptr);
  // conv2: Bf -> A [256,256,64]
  conv_mfma<32, 64, 64, 4, 0, 0, 0>
      <<<g256, 256, 0, stream>>>(Bf, wT + WOFF[2], bs[2], A, 256, 256, nullptr, nullptr);
  // conv3 + relu + pool: A -> Bf [128,128,64]
  conv_mfma<64, 64, 64, 4, 0, 0, 3>
      <<<g256, 256, 0, stream>>>(A, wT + WOFF[3], bs[3], Bf, 256, 256, nullptr, nullptr);
  // conv4 (fused up1): Bf(128² src) -> A [256,256,64]
  conv_mfma<64, 64, 64, 4, 0, 2, 0>
      <<<g256, 256, 0, stream>>>(Bf, wT + WOFF[4], bs[4], A, 256, 256, nullptr, nullptr);
  // conv5: A -> Bf [256,256,32]
  conv_mfma<64, 32, 32, 8, 0, 0, 0>
      <<<g256t, 256, 0, stream>>>(A, wT + WOFF[5], bs[5], Bf, 256, 256, nullptr, nullptr);
  // conv6 (fused up2): Bf(256² src) -> A [512,512,32]
  conv_mfma<32, 32, 32, 8, 0, 2, 0>
      <<<g512t, 256, 0, stream>>>(Bf, wT + WOFF[6], bs[6], A, 512, 512, nullptr, nullptr);
  // conv7 + tanh + fused deformed: A -> flow + def
  conv_mfma<32, 16, 2, 8, 1, 0, 2>
      <<<g512t, 256, 0, stream>>>(A, wT + WOFF[7], bs[7], flow, 512, 512, temp, def);
  // patches (overwrites the wT stash)
  {
    int total = BATCH * 256 * 64 * 64;
    patches_k<<<(total + 255) / 256, 256, 0, stream>>>(x, def, out);
  }
}

// Round 6
// 399.395 us; speedup vs baseline: 1.0762x; 1.0762x over previous
//
#include <hip/hip_runtime.h>
#include <hip/hip_bf16.h>

typedef __hip_bfloat16 bf16;
typedef unsigned short ushort_t;
typedef __attribute__((ext_vector_type(8))) short short8;
typedef __attribute__((ext_vector_type(4))) float float4v;

#define BATCH 4
#define HH 512
#define WW 512

__device__ __forceinline__ ushort_t f2bfu(float f) {
  __hip_bfloat16 h = __float2bfloat16(f);
  union { __hip_bfloat16 h; ushort_t u; } c;
  c.h = h;
  return c.u;
}
__device__ __forceinline__ float bfu2f(ushort_t u) {
  return __uint_as_float(((unsigned)u) << 16);
}

// async global->LDS DMA, 16 B per lane; LDS dest = wave-uniform base + lane*16
__device__ __forceinline__ void dma16(void* lds, const void* g) {
  __builtin_amdgcn_global_load_lds(
      (const __attribute__((address_space(1))) unsigned int*)g,
      (__attribute__((address_space(3))) unsigned int*)lds, 16, 0, 0);
}

// ---------------------------------------------------------------------------
// Weight prep: w[l] OIHW f32  ->  wT[l] = [tap(9)][COUT_PAD][CIN_PAD] bf16
// ---------------------------------------------------------------------------
struct WP { const float* w[8]; };

__global__ __launch_bounds__(256) void prep_w(WP wp, bf16* __restrict__ dst) {
  const int O[8]   = {32, 32, 64, 64, 64, 32, 32, 2};
  const int I[8]   = {3, 32, 32, 64, 64, 64, 32, 32};
  const int OP[8]  = {32, 32, 64, 64, 64, 32, 32, 16};
  const int IP[8]  = {32, 32, 32, 64, 64, 64, 32, 32};
  const int OFF[8] = {0, 9216, 18432, 36864, 73728, 110592, 129024, 138240};
  int l = blockIdx.y;
  int e = blockIdx.x * 256 + threadIdx.x;
  int n = 9 * OP[l] * IP[l];
  if (e >= n) return;
  int tap = e / (OP[l] * IP[l]);
  int rem = e - tap * OP[l] * IP[l];
  int o = rem / IP[l];
  int i = rem - o * IP[l];
  float v = 0.0f;
  if (o < O[l] && i < I[l]) v = wp.w[l][((o * I[l]) + i) * 9 + tap];
  dst[OFF[l] + e] = __float2bfloat16(v);
}

// ---------------------------------------------------------------------------
// Phase-folded conv6 weights: up2(bilinear) o conv3x3 == 4 half-res 3x3 convs.
// wP[phase][tap(j*3+k)][o][i] = sum_{r,s} w6[o][i][r][s]*R[phi][r][j]*R[psi][s][k]
// ---------------------------------------------------------------------------
__global__ __launch_bounds__(256) void prep_w6p(const float* __restrict__ w6,
                                                bf16* __restrict__ wP) {
  int e = blockIdx.x * 256 + threadIdx.x;
  if (e >= 4 * 9 * 32 * 32) return;
  int i = e & 31;
  int o = (e >> 5) & 31;
  int tap = (e >> 10) % 9;
  int phase = (e >> 10) / 9;
  int j = tap / 3, k = tap % 3;
  int phi = phase >> 1, psi = phase & 1;
  const float R[2][3][3] = {
      {{0.75f, 0.25f, 0.0f}, {0.25f, 0.75f, 0.0f}, {0.0f, 0.75f, 0.25f}},
      {{0.25f, 0.75f, 0.0f}, {0.0f, 0.75f, 0.25f}, {0.0f, 0.25f, 0.75f}}};
  float acc = 0.0f;
#pragma unroll
  for (int r = 0; r < 3; ++r)
#pragma unroll
    for (int s = 0; s < 3; ++s)
      acc += w6[((o * 32 + i) * 3 + r) * 3 + s] * R[phi][r][j] * R[psi][s][k];
  wP[e] = __float2bfloat16(acc);
}

// ---------------------------------------------------------------------------
// pack_x: NCHW f32 (3ch) -> NHWC-8 bf16 (ch 3..7 zero)
// ---------------------------------------------------------------------------
__global__ __launch_bounds__(256) void pack_x(const float* __restrict__ x,
                                              bf16* __restrict__ xp) {
  int i = blockIdx.x * 256 + threadIdx.x;  // over B*H*W
  if (i >= BATCH * HH * WW) return;
  int b = i / (HH * WW);
  int px = i - b * (HH * WW);
  union { uint4 v; ushort_t s[8]; } o;
  o.v = make_uint4(0, 0, 0, 0);
  const float* p = x + (long)b * 3 * HH * WW + px;
  o.s[0] = f2bfu(p[0]);
  o.s[1] = f2bfu(p[HH * WW]);
  o.s[2] = f2bfu(p[2 * HH * WW]);
  *(uint4*)&xp[(long)i * 8] = o.v;
}

// ---------------------------------------------------------------------------
// Implicit-GEMM 3x3 conv (pad 1) via mfma_f32_16x16x32_bf16, NHWC bf16 acts.
// Block: 256 thr (4 waves), 16x16 OUTPUT tile; wave w rows 4w..4w+3.
// WREG (CIN==32 only): all 9xMT A-fragments preloaded to registers BEFORE the
// staging barrier (loads overlap DMA latency); no w_lds at all.
// IN_MODE:  0 = NHWC bf16 same-res (DMA fast path for interior blocks)
//           2 = NHWC bf16 HALF-res source, fused x2 bilinear upsample staging
//           3 = NHWC-8 packed bf16 (conv0; ch 8..31 zero)
// OUT_MODE: 0 = NHWC bf16 (+relu)
//           2 = flow NCHW f32 (tanh) + fused deformed [B,H,W,2]
//           3 = NHWC bf16, fused relu + 2x2 maxpool (writes H/2 x W/2)
// ---------------------------------------------------------------------------
template <int CIN, int COUT, int COUTR, int ACT, int IN_MODE, int OUT_MODE,
          bool WREG>
__global__ __launch_bounds__(256) void conv_mfma(
    const void* __restrict__ in_, const bf16* __restrict__ wt,
    const float* __restrict__ bias, void* __restrict__ out_, int H, int W,
    const float* __restrict__ temp, float* __restrict__ def) {
  constexpr int MT = COUT / 16;
  constexpr int CK = 32;
  __shared__ alignas(16) bf16 in_lds[324 * CK];  // 18x18 halo x 32ch
  __shared__ alignas(16) bf16 w_lds[WREG ? 16 : 9 * COUT * CK];

  const int tid = threadIdx.x;
  const int lane = tid & 63;
  const int wid = tid >> 6;
  const int lm = lane & 15;
  const int quad = lane >> 4;
  const int x0 = blockIdx.x * 16;
  const int y0 = blockIdx.y * 16;
  const int b = blockIdx.z;

  short8 wreg[WREG ? 9 : 1][MT];
  if constexpr (WREG) {
    static_assert(CIN == CK, "WREG requires single K chunk");
#pragma unroll
    for (int tap = 0; tap < 9; ++tap)
#pragma unroll
      for (int mt = 0; mt < MT; ++mt)
        wreg[tap][mt] = *(const short8*)&wt[((long)tap * COUT + mt * 16 + lm) *
                                               CIN + quad * 8];
  }

  float4v acc[MT][4];
#pragma unroll
  for (int mt = 0; mt < MT; ++mt) {
    float4v bv;
    if constexpr (COUTR == COUT) {
      bv = *(const float4v*)(bias + mt * 16 + quad * 4);
    } else {
#pragma unroll
      for (int r = 0; r < 4; ++r) {
        int co = mt * 16 + quad * 4 + r;
        bv[r] = (co < COUTR) ? bias[co] : 0.0f;
      }
    }
#pragma unroll
    for (int nt = 0; nt < 4; ++nt) acc[mt][nt] = bv;
  }

  for (int c0 = 0; c0 < CIN; c0 += CK) {
    // ---- stage input halo tile into LDS ----
    if constexpr (IN_MODE == 3) {
      const bf16* in = (const bf16*)in_;
      for (int u = tid; u < 324 * 4; u += 256) {
        int px = u >> 2;
        int seg = u & 3;
        int hy = px / 18, hx = px - hy * 18;
        int gy = y0 - 1 + hy, gx = x0 - 1 + hx;
        uint4 v = make_uint4(0, 0, 0, 0);
        if (seg == 0 && gy >= 0 && gy < H && gx >= 0 && gx < W)
          v = *(const uint4*)(in + (((long)b * H + gy) * W + gx) * 8);
        *(uint4*)&in_lds[px * CK + seg * 8] = v;
      }
    } else if constexpr (IN_MODE == 2) {
      const bf16* in = (const bf16*)in_;
      const int Hs = H >> 1, Ws = W >> 1;
      for (int u = tid; u < 324 * 4; u += 256) {
        int px = u >> 2;
        int seg = u & 3;
        int hy = px / 18, hx = px - hy * 18;
        int gy = y0 - 1 + hy, gx = x0 - 1 + hx;
        uint4 o = make_uint4(0, 0, 0, 0);
        if (gy >= 0 && gy < H && gx >= 0 && gx < W) {
          int ys = (gy >> 1) - ((gy & 1) ? 0 : 1);
          int xs = (gx >> 1) - ((gx & 1) ? 0 : 1);
          float wy = (gy & 1) ? 0.25f : 0.75f;
          float wx = (gx & 1) ? 0.25f : 0.75f;
          int y0c = max(ys, 0), y1c = min(ys + 1, Hs - 1);
          int x0c = max(xs, 0), x1c = min(xs + 1, Ws - 1);
          const bf16* p = in + ((long)b * Hs * Ws) * CIN + c0 + seg * 8;
          union { uint4 v; ushort_t s[8]; } a00, a01, a10, a11, r;
          a00.v = *(const uint4*)(p + ((long)y0c * Ws + x0c) * CIN);
          a01.v = *(const uint4*)(p + ((long)y0c * Ws + x1c) * CIN);
          a10.v = *(const uint4*)(p + ((long)y1c * Ws + x0c) * CIN);
          a11.v = *(const uint4*)(p + ((long)y1c * Ws + x1c) * CIN);
#pragma unroll
          for (int j = 0; j < 8; ++j) {
            float f = (1.0f - wy) * ((1.0f - wx) * bfu2f(a00.s[j]) +
                                     wx * bfu2f(a01.s[j])) +
                      wy * ((1.0f - wx) * bfu2f(a10.s[j]) +
                            wx * bfu2f(a11.s[j]));
            r.s[j] = f2bfu(f);
          }
          o = r.v;
        }
        *(uint4*)&in_lds[px * CK + seg * 8] = o;
      }
    } else {
      const bool interior =
          (x0 >= 1) && (x0 + 16 <= W - 1) && (y0 >= 1) && (y0 + 16 <= H - 1);
      const bf16* in = (const bf16*)in_;
      if (interior) {
        for (int r = wid; r < 18; r += 4) {
          int gy = y0 - 1 + r;
          const bf16* gsrc = in + (((long)b * H + gy) * W + x0) * CIN + c0 +
                             (lane >> 2) * CIN + (lane & 3) * 8;
          dma16(&in_lds[(r * 18 + 1) * CK], gsrc);
        }
        for (int u = tid; u < 144; u += 256) {
          int r = u >> 3;
          int side = (u >> 2) & 1;
          int seg = u & 3;
          int gx = side ? (x0 + 16) : (x0 - 1);
          int gy = y0 - 1 + r;
          uint4 v = *(const uint4*)(in + (((long)b * H + gy) * W + gx) * CIN +
                                    c0 + seg * 8);
          *(uint4*)&in_lds[(r * 18 + (side ? 17 : 0)) * CK + seg * 8] = v;
        }
      } else {
        for (int u = tid; u < 324 * 4; u += 256) {
          int px = u >> 2;
          int seg = u & 3;
          int hy = px / 18, hx = px - hy * 18;
          int gy = y0 - 1 + hy, gx = x0 - 1 + hx;
          uint4 v = make_uint4(0, 0, 0, 0);
          if (gy >= 0 && gy < H && gx >= 0 && gx < W)
            v = *(const uint4*)(in + (((long)b * H + gy) * W + gx) * CIN + c0 +
                                seg * 8);
          *(uint4*)&in_lds[px * CK + seg * 8] = v;
        }
      }
    }
    // ---- stage weight chunk [9][COUT][CK] (non-WREG only) ----
    if constexpr (!WREG) {
      constexpr int WUNITS = 9 * COUT * CK / 8;
      for (int u = tid; u < WUNITS; u += 256) {
        int to = u >> 2;
        int seg = u & 3;
        uint4 v = *(const uint4*)(wt + (long)to * CIN + c0 + seg * 8);
        *(uint4*)&w_lds[to * CK + seg * 8] = v;
      }
    }
    __syncthreads();

    // ---- 9 taps x K=32 MFMA ----
#pragma unroll
    for (int tap = 0; tap < 9; ++tap) {
      const int r = tap / 3, s = tap - r * 3;
      short8 afrag[MT], bfrag[4];
#pragma unroll
      for (int mt = 0; mt < MT; ++mt) {
        if constexpr (WREG)
          afrag[mt] = wreg[tap][mt];
        else
          afrag[mt] = *(const short8*)&w_lds[(tap * COUT + mt * 16 + lm) * CK +
                                             quad * 8];
      }
#pragma unroll
      for (int nt = 0; nt < 4; ++nt) {
        int py = 4 * wid + nt;
        bfrag[nt] =
            *(const short8*)&in_lds[((py + r) * 18 + lm + s) * CK + quad * 8];
      }
#pragma unroll
      for (int mt = 0; mt < MT; ++mt)
#pragma unroll
        for (int nt = 0; nt < 4; ++nt)
          acc[mt][nt] = __builtin_amdgcn_mfma_f32_16x16x32_bf16(
              afrag[mt], bfrag[nt], acc[mt][nt], 0, 0, 0);
    }
    __syncthreads();
  }

  // ---- epilogue ----
  if constexpr (OUT_MODE == 3) {
    bf16* out = (bf16*)out_;
    const int Ho = H >> 1, Wo = W >> 1;
#pragma unroll
    for (int mt = 0; mt < MT; ++mt) {
#pragma unroll
      for (int g = 0; g < 2; ++g) {
        float4v m;
#pragma unroll
        for (int r = 0; r < 4; ++r)
          m[r] = fmaxf(fmaxf(acc[mt][2 * g][r], acc[mt][2 * g + 1][r]), 0.0f);
#pragma unroll
        for (int r = 0; r < 4; ++r) m[r] = fmaxf(m[r], __shfl_xor(m[r], 1, 64));
        if ((lm & 1) == 0) {
          int pyo = (y0 >> 1) + 2 * wid + g;
          int pxo = (x0 >> 1) + (lm >> 1);
          union { uint2 v; ushort_t s[4]; } pk;
#pragma unroll
          for (int r = 0; r < 4; ++r) pk.s[r] = f2bfu(m[r]);
          *(uint2*)&out[(((long)b * Ho + pyo) * Wo + pxo) * COUT + mt * 16 +
                        quad * 4] = pk.v;
        }
      }
    }
  } else {
#pragma unroll
    for (int mt = 0; mt < MT; ++mt) {
#pragma unroll
      for (int nt = 0; nt < 4; ++nt) {
        int gy = y0 + 4 * wid + nt;
        int gx = x0 + lm;
        float4v v = acc[mt][nt];
        if constexpr (OUT_MODE == 0) {
          bf16* out = (bf16*)out_;
          union { uint2 v; ushort_t s[4]; } pk;
#pragma unroll
          for (int r = 0; r < 4; ++r) pk.s[r] = f2bfu(fmaxf(v[r], 0.0f));
          *(uint2*)&out[(((long)b * H + gy) * W + gx) * COUT + mt * 16 +
                        quad * 4] = pk.v;
        } else {
          float* out = (float*)out_;
          if (quad == 0) {
            float fx = tanhf(v[0]);
            float fy = tanhf(v[1]);
            out[(((long)b * 2 + 0) * H + gy) * (long)W + gx] = fx;
            out[(((long)b * 2 + 1) * H + gy) * (long)W + gx] = fy;
            float T = temp[0];
            float2 d;
            d.x = -1.0f + gx * (2.0f / 511.0f) + fx * T;
            d.y = -1.0f + gy * (2.0f / 511.0f) + fy * T;
            *(float2*)&def[(((long)b * H + gy) * W + gx) * 2] = d;
          }
        }
      }
    }
  }
}

// ---------------------------------------------------------------------------
// conv6 fast path: phase-folded upsample+conv. Block covers a 16x16 HALF-res
// tile; one staging -> 4 phases x 9 taps of MFMA; outputs a 32x32 full-res
// tile (skipping the 1-px zero-pad ring, handled by conv_ring).
// ---------------------------------------------------------------------------
__global__ __launch_bounds__(256) void conv_up_phase(
    const bf16* __restrict__ in,  // half-res NHWC [B,Hs,Ws,32]
    const bf16* __restrict__ wP,  // [4][9][32][32]
    const float* __restrict__ bias, bf16* __restrict__ out, int Hs, int Ws) {
  constexpr int CK = 32;
  constexpr int MT = 2;
  __shared__ alignas(16) bf16 in_lds[324 * CK];

  const int tid = threadIdx.x;
  const int lane = tid & 63;
  const int wid = tid >> 6;
  const int lm = lane & 15;
  const int quad = lane >> 4;
  const int x0 = blockIdx.x * 16;
  const int y0 = blockIdx.y * 16;
  const int b = blockIdx.z;
  const int H = 2 * Hs, W = 2 * Ws;

  // stage half-res halo (CLAMPED at borders — interp semantics)
  const bool interior =
      (x0 >= 1) && (x0 + 16 <= Ws - 1) && (y0 >= 1) && (y0 + 16 <= Hs - 1);
  if (interior) {
    for (int r = wid; r < 18; r += 4) {
      int gy = y0 - 1 + r;
      const bf16* gsrc = in + (((long)b * Hs + gy) * Ws + x0) * CK +
                         (lane >> 2) * CK + (lane & 3) * 8;
      dma16(&in_lds[(r * 18 + 1) * CK], gsrc);
    }
    for (int u = tid; u < 144; u += 256) {
      int r = u >> 3;
      int side = (u >> 2) & 1;
      int seg = u & 3;
      int gx = side ? (x0 + 16) : (x0 - 1);
      int gy = y0 - 1 + r;
      uint4 v = *(const uint4*)(in + (((long)b * Hs + gy) * Ws + gx) * CK +
                                seg * 8);
      *(uint4*)&in_lds[(r * 18 + (side ? 17 : 0)) * CK + seg * 8] = v;
    }
  } else {
    for (int u = tid; u < 324 * 4; u += 256) {
      int px = u >> 2;
      int seg = u & 3;
      int hy = px / 18, hx = px - hy * 18;
      int gy = min(max(y0 - 1 + hy, 0), Hs - 1);
      int gx = min(max(x0 - 1 + hx, 0), Ws - 1);
      uint4 v =
          *(const uint4*)(in + (((long)b * Hs + gy) * Ws + gx) * CK + seg * 8);
      *(uint4*)&in_lds[px * CK + seg * 8] = v;
    }
  }
  __syncthreads();

  for (int phase = 0; phase < 4; ++phase) {
    const int phi = phase >> 1, psi = phase & 1;
    short8 wreg[9][MT];
#pragma unroll
    for (int tap = 0; tap < 9; ++tap)
#pragma unroll
      for (int mt = 0; mt < MT; ++mt)
        wreg[tap][mt] = *(const short8*)&wP[(((long)phase * 9 + tap) * 32 +
                                            mt * 16 + lm) * 32 + quad * 8];
    float4v acc[MT][4];
#pragma unroll
    for (int mt = 0; mt < MT; ++mt) {
      float4v bv = *(const float4v*)(bias + mt * 16 + quad * 4);
#pragma unroll
      for (int nt = 0; nt < 4; ++nt) acc[mt][nt] = bv;
    }
#pragma unroll
    for (int tap = 0; tap < 9; ++tap) {
      const int r = tap / 3, s = tap - r * 3;
      short8 bfrag[4];
#pragma unroll
      for (int nt = 0; nt < 4; ++nt) {
        int py = 4 * wid + nt;
        bfrag[nt] =
            *(const short8*)&in_lds[((py + r) * 18 + lm + s) * CK + quad * 8];
      }
#pragma unroll
      for (int mt = 0; mt < MT; ++mt)
#pragma unroll
        for (int nt = 0; nt < 4; ++nt)
          acc[mt][nt] = __builtin_amdgcn_mfma_f32_16x16x32_bf16(
              wreg[tap][mt], bfrag[nt], acc[mt][nt], 0, 0, 0);
    }
    // epilogue: site (y,x) -> full-res (2y+phi, 2x+psi); skip zero-pad ring
#pragma unroll
    for (int mt = 0; mt < MT; ++mt) {
#pragma unroll
      for (int nt = 0; nt < 4; ++nt) {
        int y = y0 + 4 * wid + nt;
        int x = x0 + lm;
        int Y = 2 * y + phi;
        int X = 2 * x + psi;
        if (Y >= 1 && Y <= H - 2 && X >= 1 && X <= W - 2) {
          union { uint2 v; ushort_t s[4]; } pk;
#pragma unroll
          for (int r = 0; r < 4; ++r)
            pk.s[r] = f2bfu(fmaxf(acc[mt][nt][r], 0.0f));
          *(uint2*)&out[(((long)b * H + Y) * W + X) * 32 + mt * 16 + quad * 4] =
              pk.v;
        }
      }
    }
  }
}

// ---------------------------------------------------------------------------
// conv6 ring cleanup: recompute the full-res 1-px border (zero-pad taps) the
// slow exact way. Thread = (b, ring_idx, cout-seg of 8).
// ---------------------------------------------------------------------------
__global__ __launch_bounds__(256) void conv_ring(
    const bf16* __restrict__ V,  // [B,256,256,32]
    const bf16* __restrict__ w6, // wT layout [9][32][32]
    const float* __restrict__ bias, bf16* __restrict__ out) {
  int t = blockIdx.x * 256 + threadIdx.x;
  if (t >= BATCH * 2044 * 4) return;
  int seg = t & 3;
  t >>= 2;
  int m = t % 2044;
  int b = t / 2044;
  int Y, X;
  if (m < 512) { Y = 0; X = m; }
  else if (m < 1024) { Y = 511; X = m - 512; }
  else if (m < 1534) { Y = m - 1024 + 1; X = 0; }
  else { Y = m - 1534 + 1; X = 511; }
  float acc[8];
#pragma unroll
  for (int j = 0; j < 8; ++j) acc[j] = bias[seg * 8 + j];
#pragma unroll
  for (int r = 0; r < 3; ++r) {
    int q = Y - 1 + r;
    if (q < 0 || q > 511) continue;
    int ys = (q >> 1) - ((q & 1) ? 0 : 1);
    float wy = (q & 1) ? 0.25f : 0.75f;
    int y0c = max(ys, 0), y1c = min(ys + 1, 255);
#pragma unroll
    for (int s = 0; s < 3; ++s) {
      int p = X - 1 + s;
      if (p < 0 || p > 511) continue;
      int xs = (p >> 1) - ((p & 1) ? 0 : 1);
      float wx = (p & 1) ? 0.25f : 0.75f;
      int x0c = max(xs, 0), x1c = min(xs + 1, 255);
      int tap = r * 3 + s;
      for (int is = 0; is < 4; ++is) {
        union { uint4 v; ushort_t u[8]; } a00, a01, a10, a11;
        const bf16* base = V + ((long)b * 256 * 256) * 32 + is * 8;
        a00.v = *(const uint4*)(base + ((long)y0c * 256 + x0c) * 32);
        a01.v = *(const uint4*)(base + ((long)y0c * 256 + x1c) * 32);
        a10.v = *(const uint4*)(base + ((long)y1c * 256 + x0c) * 32);
        a11.v = *(const uint4*)(base + ((long)y1c * 256 + x1c) * 32);
        float u8[8];
#pragma unroll
        for (int j = 0; j < 8; ++j)
          u8[j] = (1.0f - wy) * ((1.0f - wx) * bfu2f(a00.u[j]) +
                                 wx * bfu2f(a01.u[j])) +
                  wy * ((1.0f - wx) * bfu2f(a10.u[j]) + wx * bfu2f(a11.u[j]));
#pragma unroll
        for (int co = 0; co < 8; ++co) {
          union { uint4 v; ushort_t u[8]; } wv;
          wv.v = *(const uint4*)(w6 + ((long)tap * 32 + seg * 8 + co) * 32 +
                                 is * 8);
          float a = acc[co];
#pragma unroll
          for (int j = 0; j < 8; ++j) a += u8[j] * bfu2f(wv.u[j]);
          acc[co] = a;
        }
      }
    }
  }
  union { uint4 v; ushort_t u[8]; } o;
#pragma unroll
  for (int j = 0; j < 8; ++j) o.u[j] = f2bfu(fmaxf(acc[j], 0.0f));
  *(uint4*)&out[(((long)b * 512 + Y) * 512 + X) * 32 + seg * 8] = o.v;
}

// ---------------------------------------------------------------------------
// patches: grid_sample bilinear, zeros padding -> out [B,256,3,64,64]
// ---------------------------------------------------------------------------
__global__ __launch_bounds__(256) void patches_k(const float* __restrict__ x,
                                                 const float* __restrict__ def,
                                                 float* __restrict__ out) {
  int i = blockIdx.x * 256 + threadIdx.x;
  int pj = i & 63;
  int t = i >> 6;
  int pi = t & 63;
  t >>= 6;
  int n = t & 255;
  int b = t >> 8;
  if (b >= BATCH) return;
  int hi = n >> 4, wi = n & 15;
  const float* dptr = def + (((long)b * HH + hi * 32) * WW + wi * 32) * 2;
  float cx = dptr[0], cy = dptr[1];
  float pgx = cx + (-1.0f + pj * (2.0f / 63.0f)) * 0.125f;
  float pgy = cy + (-1.0f + pi * (2.0f / 63.0f)) * 0.125f;
  float ix = ((pgx + 1.0f) * 512.0f - 1.0f) * 0.5f;
  float iy = ((pgy + 1.0f) * 512.0f - 1.0f) * 0.5f;
  float fx0 = floorf(ix), fy0 = floorf(iy);
  float wx1 = ix - fx0, wy1 = iy - fy0;
  int x0 = (int)fx0, y0 = (int)fy0;
  int x1 = x0 + 1, y1 = y0 + 1;
  bool vx0 = (x0 >= 0) && (x0 <= 511), vx1 = (x1 >= 0) && (x1 <= 511);
  bool vy0 = (y0 >= 0) && (y0 <= 511), vy1 = (y1 >= 0) && (y1 <= 511);
  int cx0 = min(max(x0, 0), 511), cx1 = min(max(x1, 0), 511);
  int cy0 = min(max(y0, 0), 511), cy1 = min(max(y1, 0), 511);
  float w00 = (1.0f - wx1) * (1.0f - wy1) * ((vx0 && vy0) ? 1.0f : 0.0f);
  float w01 = wx1 * (1.0f - wy1) * ((vx1 && vy0) ? 1.0f : 0.0f);
  float w10 = (1.0f - wx1) * wy1 * ((vx0 && vy1) ? 1.0f : 0.0f);
  float w11 = wx1 * wy1 * ((vx1 && vy1) ? 1.0f : 0.0f);
#pragma unroll
  for (int c = 0; c < 3; ++c) {
    const float* img = x + ((long)b * 3 + c) * (HH * WW);
    float v = img[cy0 * WW + cx0] * w00 + img[cy0 * WW + cx1] * w01 +
              img[cy1 * WW + cx0] * w10 + img[cy1 * WW + cx1] * w11;
    out[(((long)b * 256 + n) * 3 + c) * 4096 + pi * 64 + pj] = v;
  }
}

// ---------------------------------------------------------------------------

extern "C" void kernel_launch(void* const* d_in, const int* in_sizes, int n_in,
                              void* d_out, int out_size, void* d_ws,
                              size_t ws_size, hipStream_t stream) {
  const float* x = (const float*)d_in[0];
  WP wp;
  const float* bs[8];
  for (int i = 0; i < 8; ++i) {
    wp.w[i] = (const float*)d_in[1 + 2 * i];
    bs[i] = (const float*)d_in[2 + 2 * i];
  }
  const float* temp = (const float*)d_in[17];

  float* out = (float*)d_out;
  float* flow = out + 12582912;  // [B,2,512,512] f32
  float* def = out + 14680064;   // [B,512,512,2] f32

  bf16* wT = (bf16*)d_out;  // weight stash; patches_k overwrites LAST
  const int WOFF[8] = {0, 9216, 18432, 36864, 73728, 110592, 129024, 138240};

  const size_t bufElems = (size_t)BATCH * 512 * 512 * 32;
  bf16* A = (bf16*)d_ws;
  bf16* Bf = A + bufElems;
  bf16* xp = Bf + bufElems;            // packed NHWC-8 input, 16.8 MB
  bf16* wP6 = xp + (size_t)BATCH * 512 * 512 * 8;  // [4][9][32][32], 72 KB

  prep_w<<<dim3(144, 8), 256, 0, stream>>>(wp, wT);
  prep_w6p<<<144, 256, 0, stream>>>(wp.w[6], wP6);
  {
    int total = BATCH * HH * WW;
    pack_x<<<(total + 255) / 256, 256, 0, stream>>>(x, xp);
  }

  dim3 g512(32, 32, BATCH);
  dim3 g256(16, 16, BATCH);

  // conv0: xp (NHWC-8) -> A [512,512,32]  (WREG)
  conv_mfma<32, 32, 32, 0, 3, 0, true>
      <<<g512, 256, 0, stream>>>(xp, wT + WOFF[0], bs[0], A, 512, 512, nullptr, nullptr);
  // conv1 + relu + pool: A -> Bf [256,256,32]  (WREG)
  conv_mfma<32, 32, 32, 0, 0, 3, true>
      <<<g512, 256, 0, stream>>>(A, wT + WOFF[1], bs[1], Bf, 512, 512, nullptr, nullptr);
  // conv2: Bf -> A [256,256,64]
  conv_mfma<32, 64, 64, 0, 0, 0, false>
      <<<g256, 256, 0, stream>>>(Bf, wT + WOFF[2], bs[2], A, 256, 256, nullptr, nullptr);
  // conv3 + relu + pool: A -> Bf [128,128,64]
  conv_mfma<64, 64, 64, 0, 0, 3, false>
      <<<g256, 256, 0, stream>>>(A, wT + WOFF[3], bs[3], Bf, 256, 256, nullptr, nullptr);
  // conv4 (fused up1): Bf(128² src) -> A [256,256,64]
  conv_mfma<64, 64, 64, 0, 2, 0, false>
      <<<g256, 256, 0, stream>>>(Bf, wT + WOFF[4], bs[4], A, 256, 256, nullptr, nullptr);
  // conv5: A -> Bf [256,256,32]
  conv_mfma<64, 32, 32, 0, 0, 0, false>
      <<<g256, 256, 0, stream>>>(A, wT + WOFF[5], bs[5], Bf, 256, 256, nullptr, nullptr);
  // conv6 (phase-folded up2+conv): Bf(256² src) -> A [512,512,32]
  conv_up_phase<<<g256, 256, 0, stream>>>(Bf, wP6, bs[6], A, 256, 256);
  // conv6 ring cleanup (zero-pad border, exact)
  {
    int total = BATCH * 2044 * 4;
    conv_ring<<<(total + 255) / 256, 256, 0, stream>>>(Bf, wT + WOFF[6], bs[6], A);
  }
  // conv7 + tanh + fused deformed: A -> flow + def  (WREG)
  conv_mfma<32, 16, 2, 1, 0, 2, true>
      <<<g512, 256, 0, stream>>>(A, wT + WOFF[7], bs[7], flow, 512, 512, temp, def);
  // patches (overwrites the wT stash)
  {
    int total = BATCH * 256 * 64 * 64;
    patches_k<<<(total + 255) / 256, 256, 0, stream>>>(x, def, out);
  }
}